// Round 5
// baseline (2546.919 us; speedup 1.0000x reference)
//
#include <hip/hip_runtime.h>

#define NN 20000
#define FF 128
#define HH 128
#define LL 4
#define OO 64
#define EE 640000
#define NEG 0.2f
#define NB ((NN + 255) / 256)   // 79 scan blocks

// ---------------- CSR build (dst-grouped, launch-invariant) ----------------

__global__ void k_init_counters(int* __restrict__ counters) {
    int i = blockIdx.x * 256 + threadIdx.x;
    if (i < NN) counters[i] = 1;  // self-loop pre-counted
}

__global__ void k_hist(const int* __restrict__ dst, int* __restrict__ counters) {
    int e = blockIdx.x * 256 + threadIdx.x;
    if (e < EE) atomicAdd(&counters[dst[e]], 1);
}

// stage 1: per-block sums of counters
__global__ void k_partial(const int* __restrict__ counters, int* __restrict__ partials) {
    __shared__ int ws[4];
    int t = threadIdx.x;
    int i = blockIdx.x * 256 + t;
    int c = (i < NN) ? counters[i] : 0;
    #pragma unroll
    for (int off = 32; off; off >>= 1) c += __shfl_xor(c, off);
    if ((t & 63) == 0) ws[t >> 6] = c;
    __syncthreads();
    if (t == 0) partials[blockIdx.x] = ws[0] + ws[1] + ws[2] + ws[3];
}

// stage 2: exclusive scan of NB partials (single block, 128 threads)
__global__ void k_scan_small(const int* __restrict__ partials, int* __restrict__ offsets) {
    __shared__ int sp[128];
    int t = threadIdx.x;
    int v = (t < NB) ? partials[t] : 0;
    sp[t] = v;
    __syncthreads();
    for (int off = 1; off < 128; off <<= 1) {
        int u = (t >= off) ? sp[t - off] : 0;
        __syncthreads();
        sp[t] += u;
        __syncthreads();
    }
    if (t < NB) offsets[t] = sp[t] - v;  // exclusive
}

// stage 3: intra-block exclusive scan + emit row_off / cursor / self-loop
__global__ void k_apply(const int* __restrict__ counters, const int* __restrict__ offsets,
                        int* __restrict__ row_off, int* __restrict__ cursor,
                        int* __restrict__ src_sorted) {
    __shared__ int sc[256];
    int t = threadIdx.x;
    int i = blockIdx.x * 256 + t;
    int c = (i < NN) ? counters[i] : 0;
    sc[t] = c;
    __syncthreads();
    for (int off = 1; off < 256; off <<= 1) {
        int u = (t >= off) ? sc[t - off] : 0;
        __syncthreads();
        sc[t] += u;
        __syncthreads();
    }
    int incl = sc[t];
    int base = offsets[blockIdx.x];
    if (i < NN) {
        int excl = base + incl - c;
        row_off[i] = excl;
        cursor[i] = excl + 1;       // slot 0 taken by self-loop
        src_sorted[excl] = i;       // self-loop edge first
        if (i == NN - 1) row_off[NN] = base + incl;
    }
}

__global__ void k_scatter(const int* __restrict__ src, const int* __restrict__ dst,
                          int* __restrict__ cursor, int* __restrict__ src_sorted) {
    int e = blockIdx.x * 256 + threadIdx.x;
    if (e < EE) {
        int p = atomicAdd(&cursor[dst[e]], 1);
        src_sorted[p] = src[e];
    }
}

// ---------------- GEMM: C[N][NCOL] = A[N][128] @ W[128][NCOL] (+bias) ----------------
// 256 threads, tile 32 rows x NCOL cols (grid = 625 for NCOL=128 -> 2.4 blk/CU).
// A tile staged in LDS once; W staged in two 64-k halves (all inner-loop operands
// from LDS; no global-latency chain). Inner loop: 4-k chunks, float4 both sides.
// ALPHAS: fused epilogue computing as_out[row] = C_row . a_s, ad_out likewise.

template <int NCOL, bool BIAS, bool ALPHAS>
__global__ void k_gemm(const float* __restrict__ A, const float* __restrict__ W,
                       const float* __restrict__ bias, float* __restrict__ C,
                       const float* __restrict__ a_s, const float* __restrict__ a_d,
                       float* __restrict__ as_out, float* __restrict__ ad_out) {
    constexpr int ROWS = 32;
    constexpr int CG = NCOL / 4;    // threads along cols (32 / 16)
    constexpr int TR = 256 / CG;    // thread-row groups  (8 / 16)
    constexpr int RPT = ROWS / TR;  // rows per thread    (4 / 2)
    __shared__ float sA[ROWS][128];
    __shared__ float sW[64][NCOL];

    int t = threadIdx.x;
    int row0 = blockIdx.x * ROWS;
    int cg = t % CG, tr = t / CG;
    int c0 = cg * 4;

    // stage A tile once: ROWS x 128 floats, coalesced float4
    for (int i = t; i < ROWS * 32; i += 256) {
        int r = i >> 5, c4 = (i & 31) << 2;
        float4 v = make_float4(0.f, 0.f, 0.f, 0.f);
        if (row0 + r < NN) v = *(const float4*)&A[(size_t)(row0 + r) * 128 + c4];
        *(float4*)&sA[r][c4] = v;
    }

    float acc[RPT][4] = {};

    #pragma unroll
    for (int half = 0; half < 2; half++) {
        if (half) __syncthreads();  // readers of previous sW done
        // stage W half: 64 x NCOL floats
        for (int i = t; i < 64 * NCOL / 4; i += 256) {
            int r = i / (NCOL / 4), c4 = (i % (NCOL / 4)) * 4;
            *(float4*)&sW[r][c4] = *(const float4*)&W[(size_t)(half * 64 + r) * NCOL + c4];
        }
        __syncthreads();

        int kb = half * 64;
        #pragma unroll
        for (int k4 = 0; k4 < 64; k4 += 4) {
            float4 w0 = *(const float4*)&sW[k4 + 0][c0];
            float4 w1 = *(const float4*)&sW[k4 + 1][c0];
            float4 w2 = *(const float4*)&sW[k4 + 2][c0];
            float4 w3 = *(const float4*)&sW[k4 + 3][c0];
            #pragma unroll
            for (int r = 0; r < RPT; r++) {
                float4 av = *(const float4*)&sA[tr * RPT + r][kb + k4];
                acc[r][0] += av.x * w0.x + av.y * w1.x + av.z * w2.x + av.w * w3.x;
                acc[r][1] += av.x * w0.y + av.y * w1.y + av.z * w2.y + av.w * w3.y;
                acc[r][2] += av.x * w0.z + av.y * w1.z + av.z * w2.z + av.w * w3.z;
                acc[r][3] += av.x * w0.w + av.y * w1.w + av.z * w2.w + av.w * w3.w;
            }
        }
    }

    #pragma unroll
    for (int r = 0; r < RPT; r++) {
        int row = row0 + tr * RPT + r;
        if (row < NN) {
            float4 v = make_float4(acc[r][0], acc[r][1], acc[r][2], acc[r][3]);
            if (BIAS) {
                v.x += bias[c0 + 0];
                v.y += bias[c0 + 1];
                v.z += bias[c0 + 2];
                v.w += bias[c0 + 3];
            }
            *(float4*)&C[(size_t)row * NCOL + c0] = v;
        }
    }

    if constexpr (ALPHAS) {
        // dot each row with a_s / a_d; reduce across the CG(=32) col-lanes
        float4 asv = *(const float4*)&a_s[c0];
        float4 adv = *(const float4*)&a_d[c0];
        #pragma unroll
        for (int r = 0; r < RPT; r++) {
            float ps = acc[r][0] * asv.x + acc[r][1] * asv.y +
                       acc[r][2] * asv.z + acc[r][3] * asv.w;
            float pd = acc[r][0] * adv.x + acc[r][1] * adv.y +
                       acc[r][2] * adv.z + acc[r][3] * adv.w;
            #pragma unroll
            for (int off = 16; off; off >>= 1) {
                ps += __shfl_xor(ps, off);
                pd += __shfl_xor(pd, off);
            }
            int row = row0 + tr * RPT + r;
            if (cg == 0 && row < NN) {
                as_out[row] = ps;
                ad_out[row] = pd;
            }
        }
    }
}

// ---------------- per-node softmax + aggregation (wave per node) ----------------
// No segment-max pass: shift by the self-loop logit (self edge is slot 0, so
// p_self = 1 and s >= 1, matching reference +1e-16 semantics; p/s is shift-
// invariant). 2 lane-groups x 8-deep predicated unroll = 16 edges in flight.

__global__ void k_aggregate(const float* __restrict__ z, const float* __restrict__ as,
                            const float* __restrict__ ad, const int* __restrict__ row_off,
                            const int* __restrict__ srcs, const float* __restrict__ bias,
                            float* __restrict__ out) {
    int node = blockIdx.x * 4 + (threadIdx.x >> 6);
    int lane = threadIdx.x & 63;
    if (node >= NN) return;
    int beg = row_off[node], end = row_off[node + 1];
    float adn = ad[node];
    float lself = as[node] + adn;
    float mx = (lself >= 0.f) ? lself : NEG * lself;  // shift = self-loop logit

    int g = lane >> 5, cl = lane & 31;
    const float4* zb = (const float4*)z;  // row stride = 32 float4
    float4 acc = make_float4(0.f, 0.f, 0.f, 0.f);
    float s = 0.f;

    for (int e = beg + g; e < end; e += 16) {
        int e1 = e + 2, e2 = e + 4, e3 = e + 6, e4 = e + 8, e5 = e + 10, e6 = e + 12, e7 = e + 14;
        int lim = end - 1;
        int i0 = e;                     // always valid (loop cond)
        int i1 = min(e1, lim), i2 = min(e2, lim), i3 = min(e3, lim);
        int i4 = min(e4, lim), i5 = min(e5, lim), i6 = min(e6, lim), i7 = min(e7, lim);
        int s0 = srcs[i0], s1 = srcs[i1], s2 = srcs[i2], s3 = srcs[i3];
        int s4 = srcs[i4], s5 = srcs[i5], s6 = srcs[i6], s7 = srcs[i7];
        float l0 = as[s0] + adn, l1 = as[s1] + adn, l2 = as[s2] + adn, l3 = as[s3] + adn;
        float l4 = as[s4] + adn, l5 = as[s5] + adn, l6 = as[s6] + adn, l7 = as[s7] + adn;
        l0 = (l0 >= 0.f) ? l0 : NEG * l0;  l1 = (l1 >= 0.f) ? l1 : NEG * l1;
        l2 = (l2 >= 0.f) ? l2 : NEG * l2;  l3 = (l3 >= 0.f) ? l3 : NEG * l3;
        l4 = (l4 >= 0.f) ? l4 : NEG * l4;  l5 = (l5 >= 0.f) ? l5 : NEG * l5;
        l6 = (l6 >= 0.f) ? l6 : NEG * l6;  l7 = (l7 >= 0.f) ? l7 : NEG * l7;
        float4 z0 = zb[(size_t)s0 * 32 + cl];
        float4 z1 = zb[(size_t)s1 * 32 + cl];
        float4 z2 = zb[(size_t)s2 * 32 + cl];
        float4 z3 = zb[(size_t)s3 * 32 + cl];
        float4 z4 = zb[(size_t)s4 * 32 + cl];
        float4 z5 = zb[(size_t)s5 * 32 + cl];
        float4 z6 = zb[(size_t)s6 * 32 + cl];
        float4 z7 = zb[(size_t)s7 * 32 + cl];
        float p0 = __expf(l0 - mx);
        float p1 = (e1 < end) ? __expf(l1 - mx) : 0.f;
        float p2 = (e2 < end) ? __expf(l2 - mx) : 0.f;
        float p3 = (e3 < end) ? __expf(l3 - mx) : 0.f;
        float p4 = (e4 < end) ? __expf(l4 - mx) : 0.f;
        float p5 = (e5 < end) ? __expf(l5 - mx) : 0.f;
        float p6 = (e6 < end) ? __expf(l6 - mx) : 0.f;
        float p7 = (e7 < end) ? __expf(l7 - mx) : 0.f;
        s += ((p0 + p1) + (p2 + p3)) + ((p4 + p5) + (p6 + p7));
        acc.x += (p0 * z0.x + p1 * z1.x + p2 * z2.x + p3 * z3.x)
               + (p4 * z4.x + p5 * z5.x + p6 * z6.x + p7 * z7.x);
        acc.y += (p0 * z0.y + p1 * z1.y + p2 * z2.y + p3 * z3.y)
               + (p4 * z4.y + p5 * z5.y + p6 * z6.y + p7 * z7.y);
        acc.z += (p0 * z0.z + p1 * z1.z + p2 * z2.z + p3 * z3.z)
               + (p4 * z4.z + p5 * z5.z + p6 * z6.z + p7 * z7.z);
        acc.w += (p0 * z0.w + p1 * z1.w + p2 * z2.w + p3 * z3.w)
               + (p4 * z4.w + p5 * z5.w + p6 * z6.w + p7 * z7.w);
    }

    // cross-group combine (lane ^ 32)
    acc.x += __shfl_xor(acc.x, 32);
    acc.y += __shfl_xor(acc.y, 32);
    acc.z += __shfl_xor(acc.z, 32);
    acc.w += __shfl_xor(acc.w, 32);
    s     += __shfl_xor(s, 32);

    if (g == 0) {
        float inv = 1.f / (s + 1e-16f);
        float4 b = ((const float4*)bias)[cl];
        float4 o;
        o.x = fmaxf(acc.x * inv + b.x, 0.f);
        o.y = fmaxf(acc.y * inv + b.y, 0.f);
        o.z = fmaxf(acc.z * inv + b.z, 0.f);
        o.w = fmaxf(acc.w * inv + b.w, 0.f);
        ((float4*)out)[(size_t)node * 32 + cl] = o;
    }
}

// ---------------- launch ----------------

extern "C" void kernel_launch(void* const* d_in, const int* in_sizes, int n_in,
                              void* d_out, int out_size, void* d_ws, size_t ws_size,
                              hipStream_t stream) {
    const float* x      = (const float*)d_in[0];
    const int*   ei     = (const int*)d_in[1];
    const float* Ws     = (const float*)d_in[2];
    const float* attS   = (const float*)d_in[3];
    const float* attD   = (const float*)d_in[4];
    const float* biases = (const float*)d_in[5];
    const float* W_out  = (const float*)d_in[6];
    const float* b_out  = (const float*)d_in[7];
    float* out = (float*)d_out;

    const int* srcp = ei;
    const int* dstp = ei + EE;

    // workspace layout (16B-aligned slices)
    char* w = (char*)d_ws;
    auto take = [&](size_t bytes) {
        char* p = w;
        w += (bytes + 15) & ~(size_t)15;
        return p;
    };
    float* zbuf       = (float*)take((size_t)NN * HH * 4);
    float* hbuf       = (float*)take((size_t)NN * HH * 4);
    float* as_v       = (float*)take((size_t)NN * 4);
    float* ad_v       = (float*)take((size_t)NN * 4);
    int*   counters   = (int*)take((size_t)NN * 4);
    int*   row_off    = (int*)take((size_t)(NN + 1) * 4);
    int*   cursor     = (int*)take((size_t)NN * 4);
    int*   src_sorted = (int*)take((size_t)(EE + NN) * 4);
    int*   partials   = (int*)take((size_t)NB * 4);
    int*   offsets    = (int*)take((size_t)NB * 4);

    // CSR build
    k_init_counters<<<(NN + 255) / 256, 256, 0, stream>>>(counters);
    k_hist<<<(EE + 255) / 256, 256, 0, stream>>>(dstp, counters);
    k_partial<<<NB, 256, 0, stream>>>(counters, partials);
    k_scan_small<<<1, 128, 0, stream>>>(partials, offsets);
    k_apply<<<NB, 256, 0, stream>>>(counters, offsets, row_off, cursor, src_sorted);
    k_scatter<<<(EE + 255) / 256, 256, 0, stream>>>(srcp, dstp, cursor, src_sorted);

    const int gemm_blocks = (NN + 31) / 32;   // 625
    const int node_blocks = (NN + 3) / 4;

    for (int l = 0; l < LL; l++) {
        const float* hin = (l == 0) ? x : hbuf;
        k_gemm<HH, false, true><<<gemm_blocks, 256, 0, stream>>>(
            hin, Ws + (size_t)l * FF * HH, nullptr, zbuf,
            attS + l * HH, attD + l * HH, as_v, ad_v);
        k_aggregate<<<node_blocks, 256, 0, stream>>>(zbuf, as_v, ad_v, row_off, src_sorted,
                                                     biases + l * HH, hbuf);
    }

    k_gemm<OO, true, false><<<gemm_blocks, 256, 0, stream>>>(
        hbuf, W_out, b_out, out, nullptr, nullptr, nullptr, nullptr);
}

// Round 6
// 347.118 us; speedup vs baseline: 7.3373x; 7.3373x over previous
//
#include <hip/hip_runtime.h>

#define NN 20000
#define FF 128
#define HH 128
#define LL 4
#define OO 64
#define EE 640000
#define NEG 0.2f
#define NB ((NN + 255) / 256)   // 79 scan blocks

// ---------------- CSR build (dst-grouped, launch-invariant) ----------------

__global__ void k_init_counters(int* __restrict__ counters) {
    int i = blockIdx.x * 256 + threadIdx.x;
    if (i < NN) counters[i] = 1;  // self-loop pre-counted
}

__global__ void k_hist(const int* __restrict__ dst, int* __restrict__ counters) {
    int e = blockIdx.x * 256 + threadIdx.x;
    if (e < EE) atomicAdd(&counters[dst[e]], 1);
}

// stage 1: per-block sums of counters
__global__ void k_partial(const int* __restrict__ counters, int* __restrict__ partials) {
    __shared__ int ws[4];
    int t = threadIdx.x;
    int i = blockIdx.x * 256 + t;
    int c = (i < NN) ? counters[i] : 0;
    #pragma unroll
    for (int off = 32; off; off >>= 1) c += __shfl_xor(c, off);
    if ((t & 63) == 0) ws[t >> 6] = c;
    __syncthreads();
    if (t == 0) partials[blockIdx.x] = ws[0] + ws[1] + ws[2] + ws[3];
}

// stage 2: exclusive scan of NB partials (single block, 128 threads)
__global__ void k_scan_small(const int* __restrict__ partials, int* __restrict__ offsets) {
    __shared__ int sp[128];
    int t = threadIdx.x;
    int v = (t < NB) ? partials[t] : 0;
    sp[t] = v;
    __syncthreads();
    for (int off = 1; off < 128; off <<= 1) {
        int u = (t >= off) ? sp[t - off] : 0;
        __syncthreads();
        sp[t] += u;
        __syncthreads();
    }
    if (t < NB) offsets[t] = sp[t] - v;  // exclusive
}

// stage 3: intra-block exclusive scan + emit row_off / cursor / self-loop
__global__ void k_apply(const int* __restrict__ counters, const int* __restrict__ offsets,
                        int* __restrict__ row_off, int* __restrict__ cursor,
                        int* __restrict__ src_sorted) {
    __shared__ int sc[256];
    int t = threadIdx.x;
    int i = blockIdx.x * 256 + t;
    int c = (i < NN) ? counters[i] : 0;
    sc[t] = c;
    __syncthreads();
    for (int off = 1; off < 256; off <<= 1) {
        int u = (t >= off) ? sc[t - off] : 0;
        __syncthreads();
        sc[t] += u;
        __syncthreads();
    }
    int incl = sc[t];
    int base = offsets[blockIdx.x];
    if (i < NN) {
        int excl = base + incl - c;
        row_off[i] = excl;
        cursor[i] = excl + 1;       // slot 0 taken by self-loop
        src_sorted[excl] = i;       // self-loop edge first
        if (i == NN - 1) row_off[NN] = base + incl;
    }
}

__global__ void k_scatter(const int* __restrict__ src, const int* __restrict__ dst,
                          int* __restrict__ cursor, int* __restrict__ src_sorted) {
    int e = blockIdx.x * 256 + threadIdx.x;
    if (e < EE) {
        int p = atomicAdd(&cursor[dst[e]], 1);
        src_sorted[p] = src[e];
    }
}

// ---------------- GEMM: C[N][NCOL] = A[N][128] @ W[128][NCOL] (+bias) ----------------
// PROVEN structure (R2/R3: 23us, VGPR 40, no spill): 256 threads, tile 64 rows x
// NCOL cols, K chunked by 32, both operands restaged per chunk from LDS.
// ALPHAS: fused epilogue computing as_out[row] = C_row . a_s, ad_out likewise.

template <int NCOL, bool BIAS, bool ALPHAS>
__global__ void k_gemm(const float* __restrict__ A, const float* __restrict__ W,
                       const float* __restrict__ bias, float* __restrict__ C,
                       const float* __restrict__ a_s, const float* __restrict__ a_d,
                       float* __restrict__ as_out, float* __restrict__ ad_out) {
    constexpr int KB = 32;
    constexpr int CG = NCOL / 4;   // threads along cols
    constexpr int TR = 256 / CG;   // thread-rows
    constexpr int RPT = 64 / TR;   // rows per thread
    __shared__ float sA[64][KB];
    __shared__ float sW[KB][NCOL];

    int t = threadIdx.x;
    int row0 = blockIdx.x * 64;
    int cg = t % CG, tr = t / CG;
    int c0 = cg * 4;

    float acc[RPT][4] = {};

    for (int k0 = 0; k0 < 128; k0 += KB) {
        for (int i = t; i < 64 * KB / 4; i += 256) {
            int r = (i * 4) / KB, kk = (i * 4) % KB;
            float4 v;
            if (row0 + r < NN)
                v = *(const float4*)&A[(size_t)(row0 + r) * 128 + k0 + kk];
            else
                v = make_float4(0.f, 0.f, 0.f, 0.f);
            *(float4*)&sA[r][kk] = v;
        }
        for (int i = t; i < KB * NCOL / 4; i += 256) {
            int r = (i * 4) / NCOL, c = (i * 4) % NCOL;
            *(float4*)&sW[r][c] = *(const float4*)&W[(size_t)(k0 + r) * NCOL + c];
        }
        __syncthreads();

        #pragma unroll
        for (int k = 0; k < KB; k++) {
            float wv[4];
            *(float4*)wv = *(const float4*)&sW[k][c0];
            #pragma unroll
            for (int r = 0; r < RPT; r++) {
                float av = sA[tr * RPT + r][k];
                acc[r][0] += av * wv[0];
                acc[r][1] += av * wv[1];
                acc[r][2] += av * wv[2];
                acc[r][3] += av * wv[3];
            }
        }
        __syncthreads();
    }

    #pragma unroll
    for (int r = 0; r < RPT; r++) {
        int row = row0 + tr * RPT + r;
        if (row < NN) {
            float4 v = make_float4(acc[r][0], acc[r][1], acc[r][2], acc[r][3]);
            if (BIAS) {
                v.x += bias[c0 + 0];
                v.y += bias[c0 + 1];
                v.z += bias[c0 + 2];
                v.w += bias[c0 + 3];
            }
            *(float4*)&C[(size_t)row * NCOL + c0] = v;
        }
    }

    if constexpr (ALPHAS) {
        // dot each row with a_s / a_d; reduce across the CG(=32) col-lanes
        float4 asv = *(const float4*)&a_s[c0];
        float4 adv = *(const float4*)&a_d[c0];
        #pragma unroll
        for (int r = 0; r < RPT; r++) {
            float ps = acc[r][0] * asv.x + acc[r][1] * asv.y +
                       acc[r][2] * asv.z + acc[r][3] * asv.w;
            float pd = acc[r][0] * adv.x + acc[r][1] * adv.y +
                       acc[r][2] * adv.z + acc[r][3] * adv.w;
            #pragma unroll
            for (int off = 16; off; off >>= 1) {
                ps += __shfl_xor(ps, off);
                pd += __shfl_xor(pd, off);
            }
            int row = row0 + tr * RPT + r;
            if (cg == 0 && row < NN) {
                as_out[row] = ps;
                ad_out[row] = pd;
            }
        }
    }
}

// ---------------- per-node softmax + aggregation (wave per node) ----------------
// No segment-max pass: shift by the self-loop logit (self edge is slot 0, so
// p_self = 1 and s >= 1, matching reference +1e-16 semantics; p/s is shift-
// invariant). 2 lane-groups x 8-deep predicated unroll = 16 edges in flight.

__global__ void k_aggregate(const float* __restrict__ z, const float* __restrict__ as,
                            const float* __restrict__ ad, const int* __restrict__ row_off,
                            const int* __restrict__ srcs, const float* __restrict__ bias,
                            float* __restrict__ out) {
    int node = blockIdx.x * 4 + (threadIdx.x >> 6);
    int lane = threadIdx.x & 63;
    if (node >= NN) return;
    int beg = row_off[node], end = row_off[node + 1];
    float adn = ad[node];
    float lself = as[node] + adn;
    float mx = (lself >= 0.f) ? lself : NEG * lself;  // shift = self-loop logit

    int g = lane >> 5, cl = lane & 31;
    const float4* zb = (const float4*)z;  // row stride = 32 float4
    float4 acc = make_float4(0.f, 0.f, 0.f, 0.f);
    float s = 0.f;

    for (int e = beg + g; e < end; e += 16) {
        int e1 = e + 2, e2 = e + 4, e3 = e + 6, e4 = e + 8, e5 = e + 10, e6 = e + 12, e7 = e + 14;
        int lim = end - 1;
        int i0 = e;                     // always valid (loop cond)
        int i1 = min(e1, lim), i2 = min(e2, lim), i3 = min(e3, lim);
        int i4 = min(e4, lim), i5 = min(e5, lim), i6 = min(e6, lim), i7 = min(e7, lim);
        int s0 = srcs[i0], s1 = srcs[i1], s2 = srcs[i2], s3 = srcs[i3];
        int s4 = srcs[i4], s5 = srcs[i5], s6 = srcs[i6], s7 = srcs[i7];
        float l0 = as[s0] + adn, l1 = as[s1] + adn, l2 = as[s2] + adn, l3 = as[s3] + adn;
        float l4 = as[s4] + adn, l5 = as[s5] + adn, l6 = as[s6] + adn, l7 = as[s7] + adn;
        l0 = (l0 >= 0.f) ? l0 : NEG * l0;  l1 = (l1 >= 0.f) ? l1 : NEG * l1;
        l2 = (l2 >= 0.f) ? l2 : NEG * l2;  l3 = (l3 >= 0.f) ? l3 : NEG * l3;
        l4 = (l4 >= 0.f) ? l4 : NEG * l4;  l5 = (l5 >= 0.f) ? l5 : NEG * l5;
        l6 = (l6 >= 0.f) ? l6 : NEG * l6;  l7 = (l7 >= 0.f) ? l7 : NEG * l7;
        float4 z0 = zb[(size_t)s0 * 32 + cl];
        float4 z1 = zb[(size_t)s1 * 32 + cl];
        float4 z2 = zb[(size_t)s2 * 32 + cl];
        float4 z3 = zb[(size_t)s3 * 32 + cl];
        float4 z4 = zb[(size_t)s4 * 32 + cl];
        float4 z5 = zb[(size_t)s5 * 32 + cl];
        float4 z6 = zb[(size_t)s6 * 32 + cl];
        float4 z7 = zb[(size_t)s7 * 32 + cl];
        float p0 = __expf(l0 - mx);
        float p1 = (e1 < end) ? __expf(l1 - mx) : 0.f;
        float p2 = (e2 < end) ? __expf(l2 - mx) : 0.f;
        float p3 = (e3 < end) ? __expf(l3 - mx) : 0.f;
        float p4 = (e4 < end) ? __expf(l4 - mx) : 0.f;
        float p5 = (e5 < end) ? __expf(l5 - mx) : 0.f;
        float p6 = (e6 < end) ? __expf(l6 - mx) : 0.f;
        float p7 = (e7 < end) ? __expf(l7 - mx) : 0.f;
        s += ((p0 + p1) + (p2 + p3)) + ((p4 + p5) + (p6 + p7));
        acc.x += (p0 * z0.x + p1 * z1.x + p2 * z2.x + p3 * z3.x)
               + (p4 * z4.x + p5 * z5.x + p6 * z6.x + p7 * z7.x);
        acc.y += (p0 * z0.y + p1 * z1.y + p2 * z2.y + p3 * z3.y)
               + (p4 * z4.y + p5 * z5.y + p6 * z6.y + p7 * z7.y);
        acc.z += (p0 * z0.z + p1 * z1.z + p2 * z2.z + p3 * z3.z)
               + (p4 * z4.z + p5 * z5.z + p6 * z6.z + p7 * z7.z);
        acc.w += (p0 * z0.w + p1 * z1.w + p2 * z2.w + p3 * z3.w)
               + (p4 * z4.w + p5 * z5.w + p6 * z6.w + p7 * z7.w);
    }

    // cross-group combine (lane ^ 32)
    acc.x += __shfl_xor(acc.x, 32);
    acc.y += __shfl_xor(acc.y, 32);
    acc.z += __shfl_xor(acc.z, 32);
    acc.w += __shfl_xor(acc.w, 32);
    s     += __shfl_xor(s, 32);

    if (g == 0) {
        float inv = 1.f / (s + 1e-16f);
        float4 b = ((const float4*)bias)[cl];
        float4 o;
        o.x = fmaxf(acc.x * inv + b.x, 0.f);
        o.y = fmaxf(acc.y * inv + b.y, 0.f);
        o.z = fmaxf(acc.z * inv + b.z, 0.f);
        o.w = fmaxf(acc.w * inv + b.w, 0.f);
        ((float4*)out)[(size_t)node * 32 + cl] = o;
    }
}

// ---------------- launch ----------------

extern "C" void kernel_launch(void* const* d_in, const int* in_sizes, int n_in,
                              void* d_out, int out_size, void* d_ws, size_t ws_size,
                              hipStream_t stream) {
    const float* x      = (const float*)d_in[0];
    const int*   ei     = (const int*)d_in[1];
    const float* Ws     = (const float*)d_in[2];
    const float* attS   = (const float*)d_in[3];
    const float* attD   = (const float*)d_in[4];
    const float* biases = (const float*)d_in[5];
    const float* W_out  = (const float*)d_in[6];
    const float* b_out  = (const float*)d_in[7];
    float* out = (float*)d_out;

    const int* srcp = ei;
    const int* dstp = ei + EE;

    // workspace layout (16B-aligned slices)
    char* w = (char*)d_ws;
    auto take = [&](size_t bytes) {
        char* p = w;
        w += (bytes + 15) & ~(size_t)15;
        return p;
    };
    float* zbuf       = (float*)take((size_t)NN * HH * 4);
    float* hbuf       = (float*)take((size_t)NN * HH * 4);
    float* as_v       = (float*)take((size_t)NN * 4);
    float* ad_v       = (float*)take((size_t)NN * 4);
    int*   counters   = (int*)take((size_t)NN * 4);
    int*   row_off    = (int*)take((size_t)(NN + 1) * 4);
    int*   cursor     = (int*)take((size_t)NN * 4);
    int*   src_sorted = (int*)take((size_t)(EE + NN) * 4);
    int*   partials   = (int*)take((size_t)NB * 4);
    int*   offsets    = (int*)take((size_t)NB * 4);

    // CSR build
    k_init_counters<<<(NN + 255) / 256, 256, 0, stream>>>(counters);
    k_hist<<<(EE + 255) / 256, 256, 0, stream>>>(dstp, counters);
    k_partial<<<NB, 256, 0, stream>>>(counters, partials);
    k_scan_small<<<1, 128, 0, stream>>>(partials, offsets);
    k_apply<<<NB, 256, 0, stream>>>(counters, offsets, row_off, cursor, src_sorted);
    k_scatter<<<(EE + 255) / 256, 256, 0, stream>>>(srcp, dstp, cursor, src_sorted);

    const int gemm_blocks = (NN + 63) / 64;   // 313
    const int node_blocks = (NN + 3) / 4;

    for (int l = 0; l < LL; l++) {
        const float* hin = (l == 0) ? x : hbuf;
        k_gemm<HH, false, true><<<gemm_blocks, 256, 0, stream>>>(
            hin, Ws + (size_t)l * FF * HH, nullptr, zbuf,
            attS + l * HH, attD + l * HH, as_v, ad_v);
        k_aggregate<<<node_blocks, 256, 0, stream>>>(zbuf, as_v, ad_v, row_off, src_sorted,
                                                     biases + l * HH, hbuf);
    }

    k_gemm<OO, true, false><<<gemm_blocks, 256, 0, stream>>>(
        hbuf, W_out, b_out, out, nullptr, nullptr, nullptr, nullptr);
}

// Round 7
// 333.387 us; speedup vs baseline: 7.6395x; 1.0412x over previous
//
#include <hip/hip_runtime.h>

#define NN 20000
#define FF 128
#define HH 128
#define LL 4
#define OO 64
#define EE 640000
#define NEG 0.2f
#define NB ((NN + 255) / 256)   // 79 scan blocks

typedef short bf16x8 __attribute__((ext_vector_type(8)));
typedef float f32x4 __attribute__((ext_vector_type(4)));

__device__ inline ushort f2bf(float f) {  // f32 -> bf16 RNE
    uint u = __float_as_uint(f);
    return (ushort)((u + 0x7fffu + ((u >> 16) & 1u)) >> 16);
}

// ---------------- CSR build (dst-grouped, launch-invariant) ----------------

__global__ void k_init_counters(int* __restrict__ counters) {
    int i = blockIdx.x * 256 + threadIdx.x;
    if (i < NN) counters[i] = 1;  // self-loop pre-counted
}

__global__ void k_hist(const int* __restrict__ dst, int* __restrict__ counters) {
    int e = blockIdx.x * 256 + threadIdx.x;
    if (e < EE) atomicAdd(&counters[dst[e]], 1);
}

__global__ void k_partial(const int* __restrict__ counters, int* __restrict__ partials) {
    __shared__ int ws[4];
    int t = threadIdx.x;
    int i = blockIdx.x * 256 + t;
    int c = (i < NN) ? counters[i] : 0;
    #pragma unroll
    for (int off = 32; off; off >>= 1) c += __shfl_xor(c, off);
    if ((t & 63) == 0) ws[t >> 6] = c;
    __syncthreads();
    if (t == 0) partials[blockIdx.x] = ws[0] + ws[1] + ws[2] + ws[3];
}

__global__ void k_scan_small(const int* __restrict__ partials, int* __restrict__ offsets) {
    __shared__ int sp[128];
    int t = threadIdx.x;
    int v = (t < NB) ? partials[t] : 0;
    sp[t] = v;
    __syncthreads();
    for (int off = 1; off < 128; off <<= 1) {
        int u = (t >= off) ? sp[t - off] : 0;
        __syncthreads();
        sp[t] += u;
        __syncthreads();
    }
    if (t < NB) offsets[t] = sp[t] - v;  // exclusive
}

__global__ void k_apply(const int* __restrict__ counters, const int* __restrict__ offsets,
                        int* __restrict__ row_off, int* __restrict__ cursor,
                        int* __restrict__ src_sorted) {
    __shared__ int sc[256];
    int t = threadIdx.x;
    int i = blockIdx.x * 256 + t;
    int c = (i < NN) ? counters[i] : 0;
    sc[t] = c;
    __syncthreads();
    for (int off = 1; off < 256; off <<= 1) {
        int u = (t >= off) ? sc[t - off] : 0;
        __syncthreads();
        sc[t] += u;
        __syncthreads();
    }
    int incl = sc[t];
    int base = offsets[blockIdx.x];
    if (i < NN) {
        int excl = base + incl - c;
        row_off[i] = excl;
        cursor[i] = excl + 1;       // slot 0 taken by self-loop
        src_sorted[excl] = i;       // self-loop edge first
        if (i == NN - 1) row_off[NN] = base + incl;
    }
}

__global__ void k_scatter(const int* __restrict__ src, const int* __restrict__ dst,
                          int* __restrict__ cursor, int* __restrict__ src_sorted) {
    int e = blockIdx.x * 256 + threadIdx.x;
    if (e < EE) {
        int p = atomicAdd(&cursor[dst[e]], 1);
        src_sorted[p] = src[e];
    }
}

// ---------------- W conversion: f32 [k][n] -> bf16 hi/lo transposed [n][k] ----------------
// wh/wl layout: layers 0..3 at l*HH*128 ([128 n][128 k]); W_out at LL*HH*128 ([64 n][128 k]).

__global__ void k_convw(const float* __restrict__ Ws, const float* __restrict__ Wout,
                        ushort* __restrict__ wh, ushort* __restrict__ wl) {
    int idx = blockIdx.x * 256 + threadIdx.x;
    const int per_l = HH * 128;
    float v;
    if (idx < LL * per_l) {
        int l = idx / per_l, rem = idx % per_l;
        int n = rem >> 7, k = rem & 127;
        v = Ws[(size_t)l * 128 * HH + (size_t)k * HH + n];
    } else {
        int j = idx - LL * per_l;
        if (j >= OO * 128) return;
        int n = j >> 7, k = j & 127;
        v = Wout[(size_t)k * OO + n];
    }
    ushort h = f2bf(v);
    float hf = __uint_as_float((uint)h << 16);
    wh[idx] = h;
    wl[idx] = f2bf(v - hf);
}

// ---------------- MFMA GEMM (bf16x3): C[N][NCOL] = A[N][128] @ W (+bias) ----------------
// 1 wave per 16 rows, no LDS. A loaded per-lane (exactly-once), converted hi/lo
// in-register; W fragments streamed from L2-hot transposed bf16 wt[n][k].
// bf16x3: A*W ~= Ah*Wh + Ah*Wl + Al*Wh (error ~2^-17 rel).
// Frag maps (guide §3, m89-verified): A row=lane&15, k=(lane>>4)*8+j;
// B col=lane&15, same k; D col=lane&15, row=(lane>>4)*4+reg.

template <int NCOL, bool BIAS, bool ALPHAS>
__global__ void k_gemm_mfma(const float* __restrict__ A, const ushort* __restrict__ wh,
                            const ushort* __restrict__ wl, const float* __restrict__ bias,
                            float* __restrict__ C,
                            const float* __restrict__ a_s, const float* __restrict__ a_d,
                            float* __restrict__ as_out, float* __restrict__ ad_out) {
    constexpr int NT = NCOL / 16;
    int l = threadIdx.x;           // 0..63
    int row0 = blockIdx.x * 16;
    int lr = l & 15, lg = l >> 4;

    // load this lane's A: row lr, k = s*32 + lg*8 + j (j=0..7), s=0..3
    const float* arow = A + (size_t)(row0 + lr) * 128;
    f32x4 af0[4], af1[4];
    #pragma unroll
    for (int s = 0; s < 4; s++) {
        af0[s] = *(const f32x4*)(arow + s * 32 + lg * 8);
        af1[s] = *(const f32x4*)(arow + s * 32 + lg * 8 + 4);
    }
    bf16x8 ah[4], al[4];
    #pragma unroll
    for (int s = 0; s < 4; s++) {
        #pragma unroll
        for (int j = 0; j < 8; j++) {
            float v = (j < 4) ? af0[s][j] : af1[s][j - 4];
            ushort h = f2bf(v);
            float hf = __uint_as_float((uint)h << 16);
            ah[s][j] = (short)h;
            al[s][j] = (short)f2bf(v - hf);
        }
    }

    f32x4 acc[NT];
    #pragma unroll
    for (int nt = 0; nt < NT; nt++) acc[nt] = (f32x4){0.f, 0.f, 0.f, 0.f};

    #pragma unroll
    for (int s = 0; s < 4; s++) {
        #pragma unroll
        for (int nt = 0; nt < NT; nt++) {
            int woff = (nt * 16 + lr) * 128 + s * 32 + lg * 8;
            bf16x8 bh = *(const bf16x8*)(wh + woff);
            bf16x8 bl = *(const bf16x8*)(wl + woff);
            acc[nt] = __builtin_amdgcn_mfma_f32_16x16x32_bf16(ah[s], bh, acc[nt], 0, 0, 0);
            acc[nt] = __builtin_amdgcn_mfma_f32_16x16x32_bf16(ah[s], bl, acc[nt], 0, 0, 0);
            acc[nt] = __builtin_amdgcn_mfma_f32_16x16x32_bf16(al[s], bh, acc[nt], 0, 0, 0);
        }
    }

    int orow = lg * 4;
    #pragma unroll
    for (int nt = 0; nt < NT; nt++) {
        #pragma unroll
        for (int r = 0; r < 4; r++) {
            float v = acc[nt][r];
            if (BIAS) v += bias[nt * 16 + lr];
            C[(size_t)(row0 + orow + r) * NCOL + nt * 16 + lr] = v;
        }
    }

    if constexpr (ALPHAS) {
        #pragma unroll
        for (int r = 0; r < 4; r++) {
            float ps = 0.f, pd = 0.f;
            #pragma unroll
            for (int nt = 0; nt < NT; nt++) {
                ps += acc[nt][r] * a_s[nt * 16 + lr];
                pd += acc[nt][r] * a_d[nt * 16 + lr];
            }
            #pragma unroll
            for (int off = 1; off < 16; off <<= 1) {
                ps += __shfl_xor(ps, off);
                pd += __shfl_xor(pd, off);
            }
            if (lr == 0) {
                as_out[row0 + orow + r] = ps;
                ad_out[row0 + orow + r] = pd;
            }
        }
    }
}

// ---------------- per-node softmax + aggregation (wave per node) ----------------
// Shift by self-loop logit (self edge slot 0 => p_self=1, s>=1; p/s shift-invariant).
// 2 lane-groups x 8-deep predicated unroll = 16 edges in flight.

__global__ void k_aggregate(const float* __restrict__ z, const float* __restrict__ as,
                            const float* __restrict__ ad, const int* __restrict__ row_off,
                            const int* __restrict__ srcs, const float* __restrict__ bias,
                            float* __restrict__ out) {
    int node = blockIdx.x * 4 + (threadIdx.x >> 6);
    int lane = threadIdx.x & 63;
    if (node >= NN) return;
    int beg = row_off[node], end = row_off[node + 1];
    float adn = ad[node];
    float lself = as[node] + adn;
    float mx = (lself >= 0.f) ? lself : NEG * lself;

    int g = lane >> 5, cl = lane & 31;
    const float4* zb = (const float4*)z;
    float4 acc = make_float4(0.f, 0.f, 0.f, 0.f);
    float s = 0.f;

    for (int e = beg + g; e < end; e += 16) {
        int e1 = e + 2, e2 = e + 4, e3 = e + 6, e4 = e + 8, e5 = e + 10, e6 = e + 12, e7 = e + 14;
        int lim = end - 1;
        int i1 = min(e1, lim), i2 = min(e2, lim), i3 = min(e3, lim);
        int i4 = min(e4, lim), i5 = min(e5, lim), i6 = min(e6, lim), i7 = min(e7, lim);
        int s0 = srcs[e], s1 = srcs[i1], s2 = srcs[i2], s3 = srcs[i3];
        int s4 = srcs[i4], s5 = srcs[i5], s6 = srcs[i6], s7 = srcs[i7];
        float l0 = as[s0] + adn, l1 = as[s1] + adn, l2 = as[s2] + adn, l3 = as[s3] + adn;
        float l4 = as[s4] + adn, l5 = as[s5] + adn, l6 = as[s6] + adn, l7 = as[s7] + adn;
        l0 = (l0 >= 0.f) ? l0 : NEG * l0;  l1 = (l1 >= 0.f) ? l1 : NEG * l1;
        l2 = (l2 >= 0.f) ? l2 : NEG * l2;  l3 = (l3 >= 0.f) ? l3 : NEG * l3;
        l4 = (l4 >= 0.f) ? l4 : NEG * l4;  l5 = (l5 >= 0.f) ? l5 : NEG * l5;
        l6 = (l6 >= 0.f) ? l6 : NEG * l6;  l7 = (l7 >= 0.f) ? l7 : NEG * l7;
        float4 z0 = zb[(size_t)s0 * 32 + cl];
        float4 z1 = zb[(size_t)s1 * 32 + cl];
        float4 z2 = zb[(size_t)s2 * 32 + cl];
        float4 z3 = zb[(size_t)s3 * 32 + cl];
        float4 z4 = zb[(size_t)s4 * 32 + cl];
        float4 z5 = zb[(size_t)s5 * 32 + cl];
        float4 z6 = zb[(size_t)s6 * 32 + cl];
        float4 z7 = zb[(size_t)s7 * 32 + cl];
        float p0 = __expf(l0 - mx);
        float p1 = (e1 < end) ? __expf(l1 - mx) : 0.f;
        float p2 = (e2 < end) ? __expf(l2 - mx) : 0.f;
        float p3 = (e3 < end) ? __expf(l3 - mx) : 0.f;
        float p4 = (e4 < end) ? __expf(l4 - mx) : 0.f;
        float p5 = (e5 < end) ? __expf(l5 - mx) : 0.f;
        float p6 = (e6 < end) ? __expf(l6 - mx) : 0.f;
        float p7 = (e7 < end) ? __expf(l7 - mx) : 0.f;
        s += ((p0 + p1) + (p2 + p3)) + ((p4 + p5) + (p6 + p7));
        acc.x += (p0 * z0.x + p1 * z1.x + p2 * z2.x + p3 * z3.x)
               + (p4 * z4.x + p5 * z5.x + p6 * z6.x + p7 * z7.x);
        acc.y += (p0 * z0.y + p1 * z1.y + p2 * z2.y + p3 * z3.y)
               + (p4 * z4.y + p5 * z5.y + p6 * z6.y + p7 * z7.y);
        acc.z += (p0 * z0.z + p1 * z1.z + p2 * z2.z + p3 * z3.z)
               + (p4 * z4.z + p5 * z5.z + p6 * z6.z + p7 * z7.z);
        acc.w += (p0 * z0.w + p1 * z1.w + p2 * z2.w + p3 * z3.w)
               + (p4 * z4.w + p5 * z5.w + p6 * z6.w + p7 * z7.w);
    }

    acc.x += __shfl_xor(acc.x, 32);
    acc.y += __shfl_xor(acc.y, 32);
    acc.z += __shfl_xor(acc.z, 32);
    acc.w += __shfl_xor(acc.w, 32);
    s     += __shfl_xor(s, 32);

    if (g == 0) {
        float inv = 1.f / (s + 1e-16f);
        float4 b = ((const float4*)bias)[cl];
        float4 o;
        o.x = fmaxf(acc.x * inv + b.x, 0.f);
        o.y = fmaxf(acc.y * inv + b.y, 0.f);
        o.z = fmaxf(acc.z * inv + b.z, 0.f);
        o.w = fmaxf(acc.w * inv + b.w, 0.f);
        ((float4*)out)[(size_t)node * 32 + cl] = o;
    }
}

// ---------------- launch ----------------

extern "C" void kernel_launch(void* const* d_in, const int* in_sizes, int n_in,
                              void* d_out, int out_size, void* d_ws, size_t ws_size,
                              hipStream_t stream) {
    const float* x      = (const float*)d_in[0];
    const int*   ei     = (const int*)d_in[1];
    const float* Ws     = (const float*)d_in[2];
    const float* attS   = (const float*)d_in[3];
    const float* attD   = (const float*)d_in[4];
    const float* biases = (const float*)d_in[5];
    const float* W_out  = (const float*)d_in[6];
    const float* b_out  = (const float*)d_in[7];
    float* out = (float*)d_out;

    const int* srcp = ei;
    const int* dstp = ei + EE;

    char* w = (char*)d_ws;
    auto take = [&](size_t bytes) {
        char* p = w;
        w += (bytes + 15) & ~(size_t)15;
        return p;
    };
    float*  zbuf       = (float*)take((size_t)NN * HH * 4);
    float*  hbuf       = (float*)take((size_t)NN * HH * 4);
    float*  as_v       = (float*)take((size_t)NN * 4);
    float*  ad_v       = (float*)take((size_t)NN * 4);
    int*    counters   = (int*)take((size_t)NN * 4);
    int*    row_off    = (int*)take((size_t)(NN + 1) * 4);
    int*    cursor     = (int*)take((size_t)NN * 4);
    int*    src_sorted = (int*)take((size_t)(EE + NN) * 4);
    int*    partials   = (int*)take((size_t)NB * 4);
    int*    offsets    = (int*)take((size_t)NB * 4);
    const int WTOT = LL * HH * 128 + OO * 128;   // 73728
    ushort* whbuf      = (ushort*)take((size_t)WTOT * 2);
    ushort* wlbuf      = (ushort*)take((size_t)WTOT * 2);

    // CSR build + weight conversion
    k_init_counters<<<(NN + 255) / 256, 256, 0, stream>>>(counters);
    k_hist<<<(EE + 255) / 256, 256, 0, stream>>>(dstp, counters);
    k_partial<<<NB, 256, 0, stream>>>(counters, partials);
    k_scan_small<<<1, 128, 0, stream>>>(partials, offsets);
    k_apply<<<NB, 256, 0, stream>>>(counters, offsets, row_off, cursor, src_sorted);
    k_scatter<<<(EE + 255) / 256, 256, 0, stream>>>(srcp, dstp, cursor, src_sorted);
    k_convw<<<(WTOT + 255) / 256, 256, 0, stream>>>(Ws, W_out, whbuf, wlbuf);

    const int gemm_blocks = NN / 16;          // 1250
    const int node_blocks = (NN + 3) / 4;

    for (int l = 0; l < LL; l++) {
        const float* hin = (l == 0) ? x : hbuf;
        k_gemm_mfma<HH, false, true><<<gemm_blocks, 64, 0, stream>>>(
            hin, whbuf + (size_t)l * HH * 128, wlbuf + (size_t)l * HH * 128,
            nullptr, zbuf, attS + l * HH, attD + l * HH, as_v, ad_v);
        k_aggregate<<<node_blocks, 256, 0, stream>>>(zbuf, as_v, ad_v, row_off, src_sorted,
                                                     biases + l * HH, hbuf);
    }

    k_gemm_mfma<OO, true, false><<<gemm_blocks, 64, 0, stream>>>(
        hbuf, whbuf + (size_t)LL * HH * 128, wlbuf + (size_t)LL * HH * 128,
        b_out, out, nullptr, nullptr, nullptr, nullptr);
}

// Round 8
// 329.928 us; speedup vs baseline: 7.7196x; 1.0105x over previous
//
#include <hip/hip_runtime.h>

#define NN 20000
#define FF 128
#define HH 128
#define LL 4
#define OO 64
#define EE 640000
#define NEG 0.2f
#define NB ((NN + 255) / 256)   // 79 scan blocks

typedef short bf16x8 __attribute__((ext_vector_type(8)));
typedef float f32x4 __attribute__((ext_vector_type(4)));

__device__ inline ushort f2bf(float f) {  // f32 -> bf16 RNE
    uint u = __float_as_uint(f);
    return (ushort)((u + 0x7fffu + ((u >> 16) & 1u)) >> 16);
}

// ---------------- CSR build (dst-grouped, launch-invariant) ----------------

__global__ void k_init_counters(int* __restrict__ counters) {
    int i = blockIdx.x * 256 + threadIdx.x;
    if (i < NN) counters[i] = 1;  // self-loop pre-counted
}

__global__ void k_hist(const int* __restrict__ dst, int* __restrict__ counters) {
    int e = blockIdx.x * 256 + threadIdx.x;
    if (e < EE) atomicAdd(&counters[dst[e]], 1);
}

__global__ void k_partial(const int* __restrict__ counters, int* __restrict__ partials) {
    __shared__ int ws[4];
    int t = threadIdx.x;
    int i = blockIdx.x * 256 + t;
    int c = (i < NN) ? counters[i] : 0;
    #pragma unroll
    for (int off = 32; off; off >>= 1) c += __shfl_xor(c, off);
    if ((t & 63) == 0) ws[t >> 6] = c;
    __syncthreads();
    if (t == 0) partials[blockIdx.x] = ws[0] + ws[1] + ws[2] + ws[3];
}

__global__ void k_scan_small(const int* __restrict__ partials, int* __restrict__ offsets) {
    __shared__ int sp[128];
    int t = threadIdx.x;
    int v = (t < NB) ? partials[t] : 0;
    sp[t] = v;
    __syncthreads();
    for (int off = 1; off < 128; off <<= 1) {
        int u = (t >= off) ? sp[t - off] : 0;
        __syncthreads();
        sp[t] += u;
        __syncthreads();
    }
    if (t < NB) offsets[t] = sp[t] - v;  // exclusive
}

__global__ void k_apply(const int* __restrict__ counters, const int* __restrict__ offsets,
                        int* __restrict__ row_off, int* __restrict__ cursor,
                        int* __restrict__ src_sorted) {
    __shared__ int sc[256];
    int t = threadIdx.x;
    int i = blockIdx.x * 256 + t;
    int c = (i < NN) ? counters[i] : 0;
    sc[t] = c;
    __syncthreads();
    for (int off = 1; off < 256; off <<= 1) {
        int u = (t >= off) ? sc[t - off] : 0;
        __syncthreads();
        sc[t] += u;
        __syncthreads();
    }
    int incl = sc[t];
    int base = offsets[blockIdx.x];
    if (i < NN) {
        int excl = base + incl - c;
        row_off[i] = excl;
        cursor[i] = excl + 1;       // slot 0 taken by self-loop
        src_sorted[excl] = i;       // self-loop edge first
        if (i == NN - 1) row_off[NN] = base + incl;
    }
}

__global__ void k_scatter(const int* __restrict__ src, const int* __restrict__ dst,
                          int* __restrict__ cursor, int* __restrict__ src_sorted) {
    int e = blockIdx.x * 256 + threadIdx.x;
    if (e < EE) {
        int p = atomicAdd(&cursor[dst[e]], 1);
        src_sorted[p] = src[e];
    }
}

// ---------------- W conversion: f32 [k][n] -> bf16 hi/lo transposed [n][k] ----------------

__global__ void k_convw(const float* __restrict__ Ws, const float* __restrict__ Wout,
                        ushort* __restrict__ wh, ushort* __restrict__ wl) {
    int idx = blockIdx.x * 256 + threadIdx.x;
    const int per_l = HH * 128;
    float v;
    if (idx < LL * per_l) {
        int l = idx / per_l, rem = idx % per_l;
        int n = rem >> 7, k = rem & 127;
        v = Ws[(size_t)l * 128 * HH + (size_t)k * HH + n];
    } else {
        int j = idx - LL * per_l;
        if (j >= OO * 128) return;
        int n = j >> 7, k = j & 127;
        v = Wout[(size_t)k * OO + n];
    }
    ushort h = f2bf(v);
    float hf = __uint_as_float((uint)h << 16);
    wh[idx] = h;
    wl[idx] = f2bf(v - hf);
}

// ---------------- wa precompute: wa[l][0][k] = (W_l @ a_s)[k], wa[l][1][k] = (W_l @ a_d)[k] ----

__global__ void k_wa(const float* __restrict__ Ws, const float* __restrict__ attS,
                     const float* __restrict__ attD, float* __restrict__ wa) {
    int t = blockIdx.x * 256 + threadIdx.x;
    if (t >= LL * 256) return;
    int l = t >> 8, rem = t & 255, which = rem >> 7, k = rem & 127;
    const float* wrow = Ws + (size_t)l * 128 * HH + (size_t)k * HH;
    const float* av = (which ? attD : attS) + l * HH;
    float s = 0.f;
    #pragma unroll 4
    for (int n = 0; n < HH; n++) s += wrow[n] * av[n];
    wa[l * 256 + which * 128 + k] = s;
}

// ---------------- MFMA GEMM (bf16x3), column-split: wave = 16 rows x 32 cols ----------------
// Grid = (NN/16) * (NCOL/32) single-wave blocks (~4.9 waves/SIMD at NCOL=128).
// A per-lane loaded once, converted hi/lo in-register; W fragments from L2-hot
// transposed bf16 [n][k]. bf16x3: A*W ~= Ah*Wh + Ah*Wl + Al*Wh.
// ALPHAS (ct==0 waves): alpha = A_row . wa (decoupled from the column split).
// Frag maps (m89): A row=lane&15, k=(lane>>4)*8+j; B col=lane&15; D col=lane&15,
// row=(lane>>4)*4+reg.

template <int NCOL, bool BIAS, bool ALPHAS>
__global__ void k_gemm_mfma(const float* __restrict__ A, const ushort* __restrict__ wh,
                            const ushort* __restrict__ wl, const float* __restrict__ bias,
                            float* __restrict__ C, const float* __restrict__ wa,
                            float* __restrict__ as_out, float* __restrict__ ad_out) {
    constexpr int CT = NCOL / 32;
    int bid = blockIdx.x;
    int rt = bid / CT, ct = bid % CT;
    int l = threadIdx.x;           // 0..63
    int row0 = rt * 16, col0 = ct * 32;
    int lr = l & 15, lg = l >> 4;

    // this lane's A: row lr, k = s*32 + lg*8 + j (j=0..7), s=0..3
    const float* arow = A + (size_t)(row0 + lr) * 128;
    f32x4 af0[4], af1[4];
    #pragma unroll
    for (int s = 0; s < 4; s++) {
        af0[s] = *(const f32x4*)(arow + s * 32 + lg * 8);
        af1[s] = *(const f32x4*)(arow + s * 32 + lg * 8 + 4);
    }
    bf16x8 ah[4], al[4];
    #pragma unroll
    for (int s = 0; s < 4; s++) {
        #pragma unroll
        for (int j = 0; j < 8; j++) {
            float v = (j < 4) ? af0[s][j] : af1[s][j - 4];
            ushort h = f2bf(v);
            float hf = __uint_as_float((uint)h << 16);
            ah[s][j] = (short)h;
            al[s][j] = (short)f2bf(v - hf);
        }
    }

    f32x4 acc[2] = {{0.f, 0.f, 0.f, 0.f}, {0.f, 0.f, 0.f, 0.f}};

    #pragma unroll
    for (int s = 0; s < 4; s++) {
        #pragma unroll
        for (int nt = 0; nt < 2; nt++) {
            int woff = (col0 + nt * 16 + lr) * 128 + s * 32 + lg * 8;
            bf16x8 bh = *(const bf16x8*)(wh + woff);
            bf16x8 bl = *(const bf16x8*)(wl + woff);
            acc[nt] = __builtin_amdgcn_mfma_f32_16x16x32_bf16(ah[s], bh, acc[nt], 0, 0, 0);
            acc[nt] = __builtin_amdgcn_mfma_f32_16x16x32_bf16(ah[s], bl, acc[nt], 0, 0, 0);
            acc[nt] = __builtin_amdgcn_mfma_f32_16x16x32_bf16(al[s], bh, acc[nt], 0, 0, 0);
        }
    }

    int orow = lg * 4;
    #pragma unroll
    for (int nt = 0; nt < 2; nt++) {
        #pragma unroll
        for (int r = 0; r < 4; r++) {
            float v = acc[nt][r];
            if (BIAS) v += bias[col0 + nt * 16 + lr];
            C[(size_t)(row0 + orow + r) * NCOL + col0 + nt * 16 + lr] = v;
        }
    }

    if constexpr (ALPHAS) {
        if (ct == 0) {
            // alpha = A_row . wa; lane covers k = s*32 + lg*8 + j
            float ps = 0.f, pd = 0.f;
            #pragma unroll
            for (int s = 0; s < 4; s++) {
                #pragma unroll
                for (int j = 0; j < 8; j++) {
                    float v = (j < 4) ? af0[s][j] : af1[s][j - 4];
                    int k = s * 32 + lg * 8 + j;
                    ps += v * wa[k];
                    pd += v * wa[128 + k];
                }
            }
            // reduce over lg (lane bits 4-5); lanes share lr
            ps += __shfl_xor(ps, 16);  pd += __shfl_xor(pd, 16);
            ps += __shfl_xor(ps, 32);  pd += __shfl_xor(pd, 32);
            if (lg == 0) {
                as_out[row0 + lr] = ps;
                ad_out[row0 + lr] = pd;
            }
        }
    }
}

// ---------------- per-node softmax + aggregation (wave per node) ----------------
// Shift by self-loop logit (self edge slot 0 => p_self=1, s>=1; p/s shift-invariant).
// 2 lane-groups x 8-deep predicated unroll = 16 edges in flight.

__global__ void k_aggregate(const float* __restrict__ z, const float* __restrict__ as,
                            const float* __restrict__ ad, const int* __restrict__ row_off,
                            const int* __restrict__ srcs, const float* __restrict__ bias,
                            float* __restrict__ out) {
    int node = blockIdx.x * 4 + (threadIdx.x >> 6);
    int lane = threadIdx.x & 63;
    if (node >= NN) return;
    int beg = row_off[node], end = row_off[node + 1];
    float adn = ad[node];
    float lself = as[node] + adn;
    float mx = (lself >= 0.f) ? lself : NEG * lself;

    int g = lane >> 5, cl = lane & 31;
    const float4* zb = (const float4*)z;
    float4 acc = make_float4(0.f, 0.f, 0.f, 0.f);
    float s = 0.f;

    for (int e = beg + g; e < end; e += 16) {
        int e1 = e + 2, e2 = e + 4, e3 = e + 6, e4 = e + 8, e5 = e + 10, e6 = e + 12, e7 = e + 14;
        int lim = end - 1;
        int i1 = min(e1, lim), i2 = min(e2, lim), i3 = min(e3, lim);
        int i4 = min(e4, lim), i5 = min(e5, lim), i6 = min(e6, lim), i7 = min(e7, lim);
        int s0 = srcs[e], s1 = srcs[i1], s2 = srcs[i2], s3 = srcs[i3];
        int s4 = srcs[i4], s5 = srcs[i5], s6 = srcs[i6], s7 = srcs[i7];
        float l0 = as[s0] + adn, l1 = as[s1] + adn, l2 = as[s2] + adn, l3 = as[s3] + adn;
        float l4 = as[s4] + adn, l5 = as[s5] + adn, l6 = as[s6] + adn, l7 = as[s7] + adn;
        l0 = (l0 >= 0.f) ? l0 : NEG * l0;  l1 = (l1 >= 0.f) ? l1 : NEG * l1;
        l2 = (l2 >= 0.f) ? l2 : NEG * l2;  l3 = (l3 >= 0.f) ? l3 : NEG * l3;
        l4 = (l4 >= 0.f) ? l4 : NEG * l4;  l5 = (l5 >= 0.f) ? l5 : NEG * l5;
        l6 = (l6 >= 0.f) ? l6 : NEG * l6;  l7 = (l7 >= 0.f) ? l7 : NEG * l7;
        float4 z0 = zb[(size_t)s0 * 32 + cl];
        float4 z1 = zb[(size_t)s1 * 32 + cl];
        float4 z2 = zb[(size_t)s2 * 32 + cl];
        float4 z3 = zb[(size_t)s3 * 32 + cl];
        float4 z4 = zb[(size_t)s4 * 32 + cl];
        float4 z5 = zb[(size_t)s5 * 32 + cl];
        float4 z6 = zb[(size_t)s6 * 32 + cl];
        float4 z7 = zb[(size_t)s7 * 32 + cl];
        float p0 = __expf(l0 - mx);
        float p1 = (e1 < end) ? __expf(l1 - mx) : 0.f;
        float p2 = (e2 < end) ? __expf(l2 - mx) : 0.f;
        float p3 = (e3 < end) ? __expf(l3 - mx) : 0.f;
        float p4 = (e4 < end) ? __expf(l4 - mx) : 0.f;
        float p5 = (e5 < end) ? __expf(l5 - mx) : 0.f;
        float p6 = (e6 < end) ? __expf(l6 - mx) : 0.f;
        float p7 = (e7 < end) ? __expf(l7 - mx) : 0.f;
        s += ((p0 + p1) + (p2 + p3)) + ((p4 + p5) + (p6 + p7));
        acc.x += (p0 * z0.x + p1 * z1.x + p2 * z2.x + p3 * z3.x)
               + (p4 * z4.x + p5 * z5.x + p6 * z6.x + p7 * z7.x);
        acc.y += (p0 * z0.y + p1 * z1.y + p2 * z2.y + p3 * z3.y)
               + (p4 * z4.y + p5 * z5.y + p6 * z6.y + p7 * z7.y);
        acc.z += (p0 * z0.z + p1 * z1.z + p2 * z2.z + p3 * z3.z)
               + (p4 * z4.z + p5 * z5.z + p6 * z6.z + p7 * z7.z);
        acc.w += (p0 * z0.w + p1 * z1.w + p2 * z2.w + p3 * z3.w)
               + (p4 * z4.w + p5 * z5.w + p6 * z6.w + p7 * z7.w);
    }

    acc.x += __shfl_xor(acc.x, 32);
    acc.y += __shfl_xor(acc.y, 32);
    acc.z += __shfl_xor(acc.z, 32);
    acc.w += __shfl_xor(acc.w, 32);
    s     += __shfl_xor(s, 32);

    if (g == 0) {
        float inv = 1.f / (s + 1e-16f);
        float4 b = ((const float4*)bias)[cl];
        float4 o;
        o.x = fmaxf(acc.x * inv + b.x, 0.f);
        o.y = fmaxf(acc.y * inv + b.y, 0.f);
        o.z = fmaxf(acc.z * inv + b.z, 0.f);
        o.w = fmaxf(acc.w * inv + b.w, 0.f);
        ((float4*)out)[(size_t)node * 32 + cl] = o;
    }
}

// ---------------- launch ----------------

extern "C" void kernel_launch(void* const* d_in, const int* in_sizes, int n_in,
                              void* d_out, int out_size, void* d_ws, size_t ws_size,
                              hipStream_t stream) {
    const float* x      = (const float*)d_in[0];
    const int*   ei     = (const int*)d_in[1];
    const float* Ws     = (const float*)d_in[2];
    const float* attS   = (const float*)d_in[3];
    const float* attD   = (const float*)d_in[4];
    const float* biases = (const float*)d_in[5];
    const float* W_out  = (const float*)d_in[6];
    const float* b_out  = (const float*)d_in[7];
    float* out = (float*)d_out;

    const int* srcp = ei;
    const int* dstp = ei + EE;

    char* w = (char*)d_ws;
    auto take = [&](size_t bytes) {
        char* p = w;
        w += (bytes + 15) & ~(size_t)15;
        return p;
    };
    float*  zbuf       = (float*)take((size_t)NN * HH * 4);
    float*  hbuf       = (float*)take((size_t)NN * HH * 4);
    float*  as_v       = (float*)take((size_t)NN * 4);
    float*  ad_v       = (float*)take((size_t)NN * 4);
    int*    counters   = (int*)take((size_t)NN * 4);
    int*    row_off    = (int*)take((size_t)(NN + 1) * 4);
    int*    cursor     = (int*)take((size_t)NN * 4);
    int*    src_sorted = (int*)take((size_t)(EE + NN) * 4);
    int*    partials   = (int*)take((size_t)NB * 4);
    int*    offsets    = (int*)take((size_t)NB * 4);
    const int WTOT = LL * HH * 128 + OO * 128;   // 73728
    ushort* whbuf      = (ushort*)take((size_t)WTOT * 2);
    ushort* wlbuf      = (ushort*)take((size_t)WTOT * 2);
    float*  wabuf      = (float*)take((size_t)LL * 256 * 4);

    // CSR build + weight conversion
    k_init_counters<<<(NN + 255) / 256, 256, 0, stream>>>(counters);
    k_hist<<<(EE + 255) / 256, 256, 0, stream>>>(dstp, counters);
    k_partial<<<NB, 256, 0, stream>>>(counters, partials);
    k_scan_small<<<1, 128, 0, stream>>>(partials, offsets);
    k_apply<<<NB, 256, 0, stream>>>(counters, offsets, row_off, cursor, src_sorted);
    k_scatter<<<(EE + 255) / 256, 256, 0, stream>>>(srcp, dstp, cursor, src_sorted);
    k_convw<<<(WTOT + 255) / 256, 256, 0, stream>>>(Ws, W_out, whbuf, wlbuf);
    k_wa<<<(LL * 256 + 255) / 256, 256, 0, stream>>>(Ws, attS, attD, wabuf);

    const int node_blocks = (NN + 3) / 4;

    for (int l = 0; l < LL; l++) {
        const float* hin = (l == 0) ? x : hbuf;
        k_gemm_mfma<HH, false, true><<<(NN / 16) * (HH / 32), 64, 0, stream>>>(
            hin, whbuf + (size_t)l * HH * 128, wlbuf + (size_t)l * HH * 128,
            nullptr, zbuf, wabuf + l * 256, as_v, ad_v);
        k_aggregate<<<node_blocks, 256, 0, stream>>>(zbuf, as_v, ad_v, row_off, src_sorted,
                                                     biases + l * HH, hbuf);
    }

    k_gemm_mfma<OO, true, false><<<(NN / 16) * (OO / 32), 64, 0, stream>>>(
        hbuf, whbuf + (size_t)LL * HH * 128, wlbuf + (size_t)LL * HH * 128,
        b_out, out, nullptr, nullptr, nullptr);
}